// Round 11
// baseline (3952.246 us; speedup 1.0000x reference)
//
#include <hip/hip_runtime.h>

typedef __attribute__((ext_vector_type(8))) short short8;
typedef __attribute__((ext_vector_type(4))) float floatx4;

#define BB    512
#define NSTEP 511
#define NG    32          // groups (16 batch rows each)
#define NM    8           // members per group (25-feature slices)
#define GWL   116         // gates LDS row stride (f32)

// ---- ws layout (u32 words) ----
#define OW2   0                          // [8][112][240 pairs] W2 slice, K covers k=32..511
#define OW1   (OW2 + 8*112*240)          // [8][112][128 pairs] W1 slice, K=256
#define OF1   (OW1 + 8*112*128)          // [8][32][256 pairs]  F1 slice, K=512
#define OF2   (OF1 + 8*32*256)           // [48][112 pairs]     F2 full, K=224
#define OFC0  (OF2 + 48*112)             // [24][48] f32 fc0^T
#define OFLG  (OFC0 + 1152)              // [32*3*8] flags (zeroed every call)
#define OEXC  (OFLG + 768)               // [32][3][8][400] f32 exchange payload
#define WS_TOT (OEXC + NG*3*NM*400)

// payload: workgroup-scope store (write-back; L1 write-through -> lands in shared L2)
#define PST(p, v) __hip_atomic_store((p), (v), __ATOMIC_RELAXED, __HIP_MEMORY_SCOPE_WORKGROUP)
// flags: agent scope
#define AST(p, v) __hip_atomic_store((p), (v), __ATOMIC_RELAXED, __HIP_MEMORY_SCOPE_AGENT)
// cross-block loads: agent scope (bypass stale L1)
#define ALD(p)    __hip_atomic_load((p), __ATOMIC_RELAXED, __HIP_MEMORY_SCOPE_AGENT)

__device__ __forceinline__ unsigned short f2bf(float f) {
    unsigned u = __float_as_uint(f);
    unsigned r = (u + 0x7fffu + ((u >> 16) & 1u)) >> 16;
    return (unsigned short)r;
}
__device__ __forceinline__ float sigm(float x) { return 1.0f / (1.0f + __expf(-x)); }
__device__ __forceinline__ float tanh_fast(float x) {
    float e = __expf(-2.0f * fabsf(x));
    float t = 1.0f - 2.0f * e / (1.0f + e);
    return copysignf(t, x);
}

// XAC K-map: [x:0..47 | h1:48..247 | 1.0@248,pad | out0:256..303 | h2:304..503 | pad]
// XA4 K-map: [o3:0..199 | 1.0@200 | pad]
__device__ __forceinline__ float w1val(int k, int grow,
        const float* l1_wih, const float* l1_whh, const float* l1_bih, const float* l1_bhh) {
    if (k < 48)  return l1_wih[grow*48 + k];
    if (k < 248) return l1_whh[grow*200 + (k - 48)];
    if (k == 248) return l1_bih[grow] + l1_bhh[grow];
    return 0.f;
}
__device__ __forceinline__ float w2val(int k, int grow,
        const float* l2_wih, const float* l2_whh, const float* l2_bih, const float* l2_bhh) {
    if (k >= 48 && k < 248) return l2_wih[grow*248 + (k - 48)];
    if (k == 248) return l2_bih[grow] + l2_bhh[grow];
    if (k >= 256 && k < 304) return l2_wih[grow*248 + 200 + (k - 256)];
    if (k >= 304 && k < 504) return l2_whh[grow*200 + (k - 304)];
    return 0.f;
}
__device__ __forceinline__ float f1val(int k, int frow,
        const float* fc1_w, const float* fc1_b) {
    if (k < 48) return fc1_w[frow*248 + 200 + k];
    if (k == 248) return fc1_b[frow];
    if (k >= 304 && k < 504) return fc1_w[frow*248 + (k - 304)];
    return 0.f;
}

// -------------------- prep: pack weights (bias folded as k-column); zero flags --------------------
__global__ void prep_kernel(const float* __restrict__ l1_wih, const float* __restrict__ l1_whh,
                            const float* __restrict__ l1_bih, const float* __restrict__ l1_bhh,
                            const float* __restrict__ l2_wih, const float* __restrict__ l2_whh,
                            const float* __restrict__ l2_bih, const float* __restrict__ l2_bhh,
                            const float* __restrict__ fc1_w, const float* __restrict__ fc1_b,
                            const float* __restrict__ fc2_w, const float* __restrict__ fc2_b,
                            const float* __restrict__ fc0_w, unsigned* __restrict__ ws)
{
    int idx = blockIdx.x * blockDim.x + threadIdx.x;
    int stride = gridDim.x * blockDim.x;
    for (int i = idx; i < OEXC; i += stride) {
        if (i < OW1) {                                   // W2 slices [m][112][240]
            int r0 = i - OW2, m = r0 / 26880, rem = r0 % 26880;
            int r = rem / 240, kp = rem % 240;
            int k0 = 32 + 2*kp, k1 = k0 + 1;
            int grow = (r < 100) ? 200*(r/25) + 25*m + (r%25) : -1;
            float a = 0.f, b = 0.f;
            if (grow >= 0) {
                a = w2val(k0, grow, l2_wih, l2_whh, l2_bih, l2_bhh);
                b = w2val(k1, grow, l2_wih, l2_whh, l2_bih, l2_bhh);
            }
            ws[i] = (unsigned)f2bf(a) | ((unsigned)f2bf(b) << 16);
        } else if (i < OF1) {                            // W1 slices [m][112][128]
            int r0 = i - OW1, m = r0 / 14336, rem = r0 % 14336;
            int r = rem / 128, kp = rem % 128;
            int k0 = 2*kp, k1 = k0 + 1;
            int grow = (r < 100) ? 200*(r/25) + 25*m + (r%25) : -1;
            float a = 0.f, b = 0.f;
            if (grow >= 0) {
                a = w1val(k0, grow, l1_wih, l1_whh, l1_bih, l1_bhh);
                b = w1val(k1, grow, l1_wih, l1_whh, l1_bih, l1_bhh);
            }
            ws[i] = (unsigned)f2bf(a) | ((unsigned)f2bf(b) << 16);
        } else if (i < OF2) {                            // F1 slices [m][32][256]
            int r0 = i - OF1, m = r0 / 8192, rem = r0 % 8192;
            int r = rem / 256, kp = rem % 256;
            int k0 = 2*kp, k1 = k0 + 1;
            float a = 0.f, b = 0.f;
            if (r < 25) {
                int frow = 25*m + r;
                a = f1val(k0, frow, fc1_w, fc1_b);
                b = f1val(k1, frow, fc1_w, fc1_b);
            }
            ws[i] = (unsigned)f2bf(a) | ((unsigned)f2bf(b) << 16);
        } else if (i < OFC0) {                           // F2 full [48][112]
            int r0 = i - OF2, n = r0 / 112, kp = r0 % 112;
            int k0 = 2*kp, k1 = k0 + 1;
            float a = (k0 < 200) ? fc2_w[n*200 + k0] : (k0 == 200 ? fc2_b[n] : 0.f);
            float b = (k1 < 200) ? fc2_w[n*200 + k1] : (k1 == 200 ? fc2_b[n] : 0.f);
            ws[i] = (unsigned)f2bf(a) | ((unsigned)f2bf(b) << 16);
        } else if (i < OFLG) {                           // fc0^T f32
            int r = i - OFC0, k = r / 48, j = r % 48;
            ws[i] = __float_as_uint(fc0_w[j*24 + k]);
        } else {
            ws[i] = 0u;                                  // flags := 0 every call
        }
    }
}

// write one bf16 element (row m, k-index k) into a pre-fragmented A-buffer
__device__ __forceinline__ void put16(short8* buf, int k, int m, unsigned short v) {
    int kt = k >> 5, kk = k & 31;
    ((unsigned short*)buf)[(((kt << 6) + m + ((kk >> 3) << 4)) << 3) + (kk & 7)] = v;
}

// -------------------- main: 256 blocks (32 groups x 8 members), weight-stationary --------------------
__global__ __launch_bounds__(1024, 4)
void lstm_sync(const float* __restrict__ tactiles, const float* __restrict__ actions,
               const float* __restrict__ fc0_b, const int* __restrict__ ctxp,
               unsigned* __restrict__ wsu, float* __restrict__ out)
{
    const int tid  = threadIdx.x;
    const int lane = tid & 63, wave = tid >> 6;
    const int ln   = lane & 15, hi = lane >> 4;
    const int g    = blockIdx.x % NG;
    const int m    = blockIdx.x / NG;
    const int r0   = g * 16;
    const int ctx  = ctxp[0];

    const short8* ws8 = (const short8*)wsu;
    unsigned* flg = wsu + OFLG;
    float*    exc = (float*)(wsu + OEXC);

    __shared__ short8 sW1[112 * 33];   // W1 slice: row*33 + kf*4 + hi
    __shared__ short8 sF1[32 * 65];    // F1 slice: row*65 + kf*4 + hi (K=512)
    __shared__ short8 XAC[16 * 64];    // unified A-buffer, K=512
    __shared__ short8 XA4[7 * 64];     // [o3 | 1.0 | pad], K=224
    __shared__ float gates[16 * GWL];
    __shared__ float f0bs[48];
    __shared__ float fc0s[24 * 48];
    __shared__ float st6[16][6], ac6[16][6];

    // ---- init: weights -> LDS/regs (once) ----
    {
        const short8* w1b = ws8 + OW1/4 + m * 3584;          // 112*128/4
        for (int i = tid; i < 3584; i += 1024) sW1[(i >> 5) * 33 + (i & 31)] = w1b[i];
        const short8* f1b = ws8 + OF1/4 + m * 2048;          // 32*256/4
        for (int i = tid; i < 2048; i += 1024) sF1[(i >> 6) * 65 + (i & 63)] = f1b[i];
        short8 z = {0,0,0,0,0,0,0,0};
        for (int i = tid; i < 1024 + 448; i += 1024) {
            if (i < 1024) XAC[i] = z;
            else XA4[i - 1024] = z;
        }
    }
    short8 wreg[15];                   // waves 0..6: W2 slice rows; waves 8..10: F2 rows
    {
        short8 z = {0,0,0,0,0,0,0,0};
        #pragma unroll
        for (int kf = 0; kf < 15; ++kf) wreg[kf] = z;
        if (wave < 7) {
            const short8* w2b = ws8 + OW2/4 + (size_t)m * 6720;   // 112*240/4
            const int rr = wave * 16 + ln;
            #pragma unroll
            for (int kf = 0; kf < 15; ++kf) wreg[kf] = w2b[rr * 60 + kf * 4 + hi];
        } else if (wave >= 8 && wave < 11) {
            const short8* f2b = ws8 + OF2/4;                      // 48*112/4
            const int rr = (wave - 8) * 16 + ln;
            #pragma unroll
            for (int kf = 0; kf < 7; ++kf) wreg[kf] = f2b[rr * 28 + kf * 4 + hi];
        }
    }
    if (tid < 48) f0bs[tid] = fc0_b[tid];
    for (int i = tid; i < 1152; i += 1024) fc0s[i] = __uint_as_float(wsu[OFC0 + i]);
    if (tid < 96) { int r = tid / 6, k = tid % 6; st6[r][k] = actions[(size_t)(r0 + r) * 6 + k]; }
    __syncthreads();
    if (tid < 16) {                    // constant-1 bias columns (never overwritten)
        put16(XAC, 248, tid, (unsigned short)0x3F80);
        put16(XA4, 200, tid, (unsigned short)0x3F80);
    }
    float c1r = 0.f, c2r = 0.f;
    __syncthreads();

    for (int t = 0; t < NSTEP; ++t) {
        // ---- P0: context x from tactiles ----
        if (t < ctx) {
            if (tid < 768) {
                int r = tid / 48, j = tid % 48;
                put16(XAC, j, r, f2bf(tactiles[((size_t)t * BB + r0 + r) * 48 + j]));
            }
            __syncthreads();
        }

        // ---- A: gates1 = XAC[kt 0..7] @ W1_slice (waves 0..6) + ac6 prefetch ----
        if (wave < 7) {
            floatx4 acc = {0.f, 0.f, 0.f, 0.f};
            const int rbase = (wave * 16 + ln) * 33 + hi;
            #pragma unroll
            for (int kf = 0; kf < 8; ++kf)
                acc = __builtin_amdgcn_mfma_f32_16x16x32_bf16(XAC[(kf << 6) + lane], sW1[rbase + kf*4], acc, 0, 0, 0);
            int col = wave * 16 + ln, m0 = hi * 4;
            gates[(m0+0)*GWL + col] = acc[0];
            gates[(m0+1)*GWL + col] = acc[1];
            gates[(m0+2)*GWL + col] = acc[2];
            gates[(m0+3)*GWL + col] = acc[3];
        }
        if (tid >= 928) {
            int q = tid - 928, r = q / 6, k = q % 6;
            ac6[r][k] = actions[((size_t)(t + 1) * BB + r0 + r) * 6 + k];
        }
        __syncthreads();

        // ---- pw1: h1/c1 (tid<400, bias pre-folded) ∥ out0 (tid>=400) ----
        if (tid < 400) {
            int r = tid / 25, f = tid % 25;
            float gi = gates[r*GWL + f];
            float gf = gates[r*GWL + 25 + f];
            float gg = gates[r*GWL + 50 + f];
            float go = gates[r*GWL + 75 + f];
            float c = sigm(gf) * c1r + sigm(gi) * tanh_fast(gg);
            c1r = c;
            float h = sigm(go) * tanh_fast(c);
            put16(XAC, 48 + 25*m + f, r, f2bf(h));
            PST(&exc[((g*3 + 0)*NM + m)*400 + tid], h);
        } else {
            int q = tid - 400;
            #pragma unroll
            for (int rep = 0; rep < 2; ++rep) {
                int item = q + rep * 624;
                if (item < 768) {
                    int r = item / 48, j = item % 48;
                    float acc = f0bs[j];
                    #pragma unroll
                    for (int k = 0; k < 24; ++k) {
                        float tv = (k < 12) ? st6[r][k % 6] : ac6[r][k % 6];
                        acc += tv * fc0s[k * 48 + j];
                    }
                    put16(XAC, 256 + j, r, f2bf(fmaxf(acc, 0.f)));
                }
            }
        }
        __syncthreads();   // payload drained to L2

        // ---- exchange h1 (per-wave poll, no extra barrier) ----
        if (tid == 0) AST(&flg[(g*3 + 0)*NM + m], (unsigned)(t + 1));
        {
            unsigned got = (lane < NM) ? ALD(&flg[(g*3 + 0)*NM + lane]) : (unsigned)(t + 1);
            while (__ballot(got != (unsigned)(t + 1)) != 0ULL) {
                __builtin_amdgcn_s_sleep(1);
                if (lane < NM) got = ALD(&flg[(g*3 + 0)*NM + lane]);
            }
        }
        for (int q = tid; q < 3200; q += 1024) {
            int mm = q / 400;
            if (mm == m) continue;
            int qq = q % 400, r = qq / 25, f = qq % 25;
            float v = ALD(&exc[((g*3 + 0)*NM + mm)*400 + qq]);
            put16(XAC, 48 + 25*mm + f, r, f2bf(v));
        }
        __syncthreads();

        // ---- B: gates2 = XAC[kt 1..15] @ W2_slice (register weights, waves 0..6) ----
        if (wave < 7) {
            floatx4 acc = {0.f, 0.f, 0.f, 0.f};
            #pragma unroll
            for (int kf = 0; kf < 15; ++kf)
                acc = __builtin_amdgcn_mfma_f32_16x16x32_bf16(XAC[((kf + 1) << 6) + lane], wreg[kf], acc, 0, 0, 0);
            int col = wave * 16 + ln, m0 = hi * 4;
            gates[(m0+0)*GWL + col] = acc[0];
            gates[(m0+1)*GWL + col] = acc[1];
            gates[(m0+2)*GWL + col] = acc[2];
            gates[(m0+3)*GWL + col] = acc[3];
        }
        __syncthreads();

        // ---- pw2: h2/c2 (bias folded); publish ----
        if (tid < 400) {
            int r = tid / 25, f = tid % 25;
            float gi = gates[r*GWL + f];
            float gf = gates[r*GWL + 25 + f];
            float gg = gates[r*GWL + 50 + f];
            float go = gates[r*GWL + 75 + f];
            float c = sigm(gf) * c2r + sigm(gi) * tanh_fast(gg);
            c2r = c;
            float h = sigm(go) * tanh_fast(c);
            put16(XAC, 304 + 25*m + f, r, f2bf(h));
            PST(&exc[((g*3 + 1)*NM + m)*400 + tid], h);
        }
        __syncthreads();

        // ---- exchange h2 ----
        if (tid == 0) AST(&flg[(g*3 + 1)*NM + m], (unsigned)(t + 1));
        {
            unsigned got = (lane < NM) ? ALD(&flg[(g*3 + 1)*NM + lane]) : (unsigned)(t + 1);
            while (__ballot(got != (unsigned)(t + 1)) != 0ULL) {
                __builtin_amdgcn_s_sleep(1);
                if (lane < NM) got = ALD(&flg[(g*3 + 1)*NM + lane]);
            }
        }
        for (int q = tid; q < 3200; q += 1024) {
            int mm = q / 400;
            if (mm == m) continue;
            int qq = q % 400, r = qq / 25, f = qq % 25;
            float v = ALD(&exc[((g*3 + 1)*NM + mm)*400 + qq]);
            put16(XAC, 304 + 25*mm + f, r, f2bf(v));
        }
        __syncthreads();

        // ---- C: fc1 slice = XAC[kt 0..15] @ F1_slice (waves 0..1) ----
        if (wave < 2) {
            floatx4 acc = {0.f, 0.f, 0.f, 0.f};
            const int rbase = (wave * 16 + ln) * 65 + hi;
            #pragma unroll
            for (int kf = 0; kf < 16; ++kf)
                acc = __builtin_amdgcn_mfma_f32_16x16x32_bf16(XAC[(kf << 6) + lane], sF1[rbase + kf*4], acc, 0, 0, 0);
            int col = wave * 16 + ln, m0 = hi * 4;
            gates[(m0+0)*GWL + col] = acc[0];
            gates[(m0+1)*GWL + col] = acc[1];
            gates[(m0+2)*GWL + col] = acc[2];
            gates[(m0+3)*GWL + col] = acc[3];
        }
        __syncthreads();

        // ---- pw3: o3 = tanh (bias folded); publish ----
        if (tid < 400) {
            int r = tid / 25, f = tid % 25;
            float v = tanh_fast(gates[r*GWL + f]);
            put16(XA4, 25*m + f, r, f2bf(v));
            PST(&exc[((g*3 + 2)*NM + m)*400 + tid], v);
        }
        __syncthreads();

        // ---- exchange o3 ----
        if (tid == 0) AST(&flg[(g*3 + 2)*NM + m], (unsigned)(t + 1));
        {
            unsigned got = (lane < NM) ? ALD(&flg[(g*3 + 2)*NM + lane]) : (unsigned)(t + 1);
            while (__ballot(got != (unsigned)(t + 1)) != 0ULL) {
                __builtin_amdgcn_s_sleep(1);
                if (lane < NM) got = ALD(&flg[(g*3 + 2)*NM + lane]);
            }
        }
        for (int q = tid; q < 3200; q += 1024) {
            int mm = q / 400;
            if (mm == m) continue;
            int qq = q % 400, r = qq / 25, f = qq % 25;
            float v = ALD(&exc[((g*3 + 2)*NM + mm)*400 + qq]);
            put16(XA4, 25*mm + f, r, f2bf(v));
        }
        __syncthreads();

        // ---- D: fc2 full = XA4 @ F2 (register weights, waves 8..10) ----
        if (wave >= 8 && wave < 11) {
            floatx4 acc = {0.f, 0.f, 0.f, 0.f};
            #pragma unroll
            for (int kf = 0; kf < 7; ++kf)
                acc = __builtin_amdgcn_mfma_f32_16x16x32_bf16(XA4[(kf << 6) + lane], wreg[kf], acc, 0, 0, 0);
            int col = (wave - 8) * 16 + ln, m0 = hi * 4;
            gates[(m0+0)*GWL + col] = acc[0];
            gates[(m0+1)*GWL + col] = acc[1];
            gates[(m0+2)*GWL + col] = acc[2];
            gates[(m0+3)*GWL + col] = acc[3];
        }
        __syncthreads();

        // ---- pw4: out4 = tanh (bias folded); store (member 0); feed back as next x ----
        if (tid < 768) {
            int r = tid / 48, j = tid % 48;
            float v = tanh_fast(gates[r*GWL + j]);
            if (t + 1 >= ctx) put16(XAC, j, r, f2bf(v));
            if (m == 0 && t >= ctx - 1)
                out[((size_t)(t - (ctx - 1)) * BB + r0 + r) * 48 + j] = v;
        }
        __syncthreads();
    }
}

extern "C" void kernel_launch(void* const* d_in, const int* in_sizes, int n_in,
                              void* d_out, int out_size, void* d_ws, size_t ws_size,
                              hipStream_t stream)
{
    const float* tactiles = (const float*)d_in[0];
    const float* actions  = (const float*)d_in[1];
    const float* fc0_w    = (const float*)d_in[2];
    const float* fc0_b    = (const float*)d_in[3];
    const float* l1_wih   = (const float*)d_in[4];
    const float* l1_whh   = (const float*)d_in[5];
    const float* l1_bih   = (const float*)d_in[6];
    const float* l1_bhh   = (const float*)d_in[7];
    const float* l2_wih   = (const float*)d_in[8];
    const float* l2_whh   = (const float*)d_in[9];
    const float* l2_bih   = (const float*)d_in[10];
    const float* l2_bhh   = (const float*)d_in[11];
    const float* fc1_w    = (const float*)d_in[12];
    const float* fc1_b    = (const float*)d_in[13];
    const float* fc2_w    = (const float*)d_in[14];
    const float* fc2_b    = (const float*)d_in[15];
    const int*   ctxp     = (const int*)d_in[16];
    unsigned* ws = (unsigned*)d_ws;
    float* out = (float*)d_out;

    hipLaunchKernelGGL(prep_kernel, dim3(512), dim3(256), 0, stream,
                       l1_wih, l1_whh, l1_bih, l1_bhh,
                       l2_wih, l2_whh, l2_bih, l2_bhh,
                       fc1_w, fc1_b, fc2_w, fc2_b, fc0_w, ws);
    hipLaunchKernelGGL(lstm_sync, dim3(256), dim3(1024), 0, stream,
                       tactiles, actions, fc0_b, ctxp, ws, out);
}